// Round 18
// baseline (494.716 us; speedup 1.0000x reference)
//
#include <hip/hip_runtime.h>
#include <hip/hip_bf16.h>

// GCN: 4 layers, D^{-1/2}(A+I)D^{-1/2} aggregation, log_softmax output.
// CSR per call (bucketed build); v = dinv*(h@W) pre-scale, CSR gather,
// post-scale dinv[dst], self-loop folded. Layer1/4 transform BEFORE agg.
// R6 bucket build; R8 gather hoist; R10 t768 R6-form; R11/R13 overlap;
// R14 bf16 gather rows (aggs latency-bound -> null; stop agg work).
// R15: single front dispatch: bucket blocks signal device-scope done-counter
//      (threadfence+atomicAdd); 128 build blocks spin+acquire-fence then
//      build; t768 blocks run free. Removes D1->D2 drain serialization
//      (build no longer waits on t768-A tail). parts -> bf16 (halve
//      parts round-trip).

#define DIVUP(a, b) (((a) + (b) - 1) / (b))
#define NBUCK 128
#define BSHIFT 10
#define BCAP 36864

__device__ __forceinline__ int load_idx(const void* ei, int is64, size_t pos) {
    if (is64) return (int)((const long long*)ei)[pos];
    return ((const int*)ei)[pos];
}

// bf16x4 (uint2) <-> float4
__device__ __forceinline__ float4 bf2f4(uint2 q) {
    float4 f;
    f.x = __uint_as_float(q.x << 16);
    f.y = __uint_as_float(q.x & 0xFFFF0000u);
    f.z = __uint_as_float(q.y << 16);
    f.w = __uint_as_float(q.y & 0xFFFF0000u);
    return f;
}
__device__ __forceinline__ unsigned bf1(float v) {
    unsigned u = __float_as_uint(v);
    u += 0x7FFFu + ((u >> 16) & 1u);  // RNE
    return u >> 16;
}
__device__ __forceinline__ uint2 f42bf(float4 f) {
    uint2 q;
    q.x = bf1(f.x) | (bf1(f.y) << 16);
    q.y = bf1(f.z) | (bf1(f.w) << 16);
    return q;
}

// ---------- init: detect edge dtype + zero gcur/done/pad rows ----------
__global__ void k_init(const void* ei, int* flag, int* gcur, int* done,
                       uint2* bufU, uint2* bufA, float4* u4p, int n) {
    int t = threadIdx.x;  // 256
    if (t < 64) {
        const int* p = (const int*)ei;
        bool z = (p[2 * t + 1] == 0);
        unsigned long long m = __ballot(z);
        if (t == 0) *flag = (m == ~0ULL) ? 1 : 0;
    } else if (t < 192) {
        gcur[t - 64] = 0;
    } else if (t < 196) {
        bufU[(size_t)n * 4 + (t - 192)] = make_uint2(0u, 0u);
    } else if (t >= 200 && t < 204) {
        bufA[(size_t)n * 4 + (t - 200)] = make_uint2(0u, 0u);
    } else if (t == 208) {
        u4p[n] = make_float4(0.f, 0.f, 0.f, 0.f);
    } else if (t == 209) {
        *done = 0;
    }
}

__device__ __forceinline__ void fma4(float s, const float4 w, float4& a) {
    a.x = fmaf(s, w.x, a.x);
    a.y = fmaf(s, w.y, a.y);
    a.z = fmaf(s, w.z, a.z);
    a.w = fmaf(s, w.w, a.w);
}

// ---------- fused front: bucket (signal) | build (spin) | t768 ----------
__global__ void k_front(const void* __restrict__ ei, const int* __restrict__ flag,
                        int* __restrict__ gcur, int* __restrict__ done,
                        int2* __restrict__ ebuf, int E, int nbB,
                        int* __restrict__ offs, int* __restrict__ cnt,
                        float* __restrict__ dinv, int* __restrict__ col,
                        const float* __restrict__ x, const float* __restrict__ W,
                        uint2* __restrict__ parts, int n) {
    __shared__ float smem[8192];  // 32KB union
    int tid = threadIdx.x;
    int bid = blockIdx.x;

    if (bid < nbB) {
        // ================= bucket branch =================
        int* hist = (int*)smem;
        int* base = hist + NBUCK;
        if (tid < NBUCK) hist[tid] = 0;
        __syncthreads();
        int is64 = *flag;
        int ebase = bid * 2048 + tid;
        int s[8], d[8], r[8], bk[8];
        bool ok[8];
#pragma unroll
        for (int j = 0; j < 8; ++j) {
            int e = ebase + j * 256;
            ok[j] = (e < E);
            s[j] = ok[j] ? load_idx(ei, is64, (size_t)e) : 0;
            d[j] = ok[j] ? load_idx(ei, is64, (size_t)E + e) : 0;
            bk[j] = d[j] >> BSHIFT;
        }
#pragma unroll
        for (int j = 0; j < 8; ++j)
            r[j] = ok[j] ? atomicAdd(&hist[bk[j]], 1) : 0;
        __syncthreads();
        if (tid < NBUCK && hist[tid] > 0)
            base[tid] = atomicAdd(&gcur[tid], hist[tid]);
        __syncthreads();
#pragma unroll
        for (int j = 0; j < 8; ++j)
            if (ok[j])
                ebuf[(size_t)bk[j] * BCAP + base[bk[j]] + r[j]] = make_int2(s[j], d[j]);
        // signal: all this block's ebuf/gcur writes drained by syncthreads
        __syncthreads();
        if (tid == 0) {
            __threadfence();          // device-scope release
            atomicAdd(done, 1);
        }
        return;
    }

    if (bid < nbB + NBUCK) {
        // ================= build branch (spin until all bucket done) ====
        if (tid == 0) {
            while (atomicAdd(done, 0) < nbB) __builtin_amdgcn_s_sleep(8);
            __threadfence();          // device-scope acquire
        }
        __syncthreads();
        int* deg = (int*)smem;      // [1024]
        int* ps  = deg + 1024;      // [256]
        int* pbb = deg + 1280;      // [1]
        int b = bid - nbB;
        int lo = b << BSHIFT;
        deg[tid] = 0; deg[tid + 256] = 0; deg[tid + 512] = 0; deg[tid + 768] = 0;
        if (tid < NBUCK) ps[tid] = (tid < b) ? gcur[tid] : 0;
        __syncthreads();
        for (int off = 1; off < NBUCK; off <<= 1) {
            int add = (tid >= off && tid < NBUCK) ? ps[tid - off] : 0;
            __syncthreads();
            if (tid < NBUCK) ps[tid] += add;
            __syncthreads();
        }
        if (tid == NBUCK - 1) *pbb = ps[tid];
        __syncthreads();
        int bb = *pbb;
        int S = gcur[b];
        const int2* eb = ebuf + (size_t)b * BCAP;
        for (int i = tid; i < S; i += 1024) {
            bool o1 = i + 256 < S, o2 = i + 512 < S, o3 = i + 768 < S;
            int2 e0 = eb[i];
            int2 e1 = o1 ? eb[i + 256] : e0;
            int2 e2 = o2 ? eb[i + 512] : e0;
            int2 e3 = o3 ? eb[i + 768] : e0;
            atomicAdd(&deg[e0.y - lo], 1);
            if (o1) atomicAdd(&deg[e1.y - lo], 1);
            if (o2) atomicAdd(&deg[e2.y - lo], 1);
            if (o3) atomicAdd(&deg[e3.y - lo], 1);
        }
        __syncthreads();
        int d0 = deg[4 * tid], d1 = deg[4 * tid + 1];
        int d2 = deg[4 * tid + 2], d3 = deg[4 * tid + 3];
        int quad = d0 + d1 + d2 + d3;
        ps[tid] = quad;
        __syncthreads();
        for (int off = 1; off < 256; off <<= 1) {
            int add = (tid >= off) ? ps[tid - off] : 0;
            __syncthreads();
            ps[tid] += add;
            __syncthreads();
        }
        int o0 = bb + ps[tid] - quad;
        int o1v = o0 + d0, o2v = o1v + d1, o3v = o2v + d2;
        deg[4 * tid] = o0; deg[4 * tid + 1] = o1v;
        deg[4 * tid + 2] = o2v; deg[4 * tid + 3] = o3v;
        int gg = lo + 4 * tid;
        if (gg < n)     { offs[gg] = o0;      cnt[gg] = d0;     dinv[gg] = rsqrtf((float)(d0 + 1)); }
        if (gg + 1 < n) { offs[gg + 1] = o1v; cnt[gg + 1] = d1; dinv[gg + 1] = rsqrtf((float)(d1 + 1)); }
        if (gg + 2 < n) { offs[gg + 2] = o2v; cnt[gg + 2] = d2; dinv[gg + 2] = rsqrtf((float)(d2 + 1)); }
        if (gg + 3 < n) { offs[gg + 3] = o3v; cnt[gg + 3] = d3; dinv[gg + 3] = rsqrtf((float)(d3 + 1)); }
        __syncthreads();
        for (int i = tid; i < S; i += 1024) {
            bool o1 = i + 256 < S, o2 = i + 512 < S, o3 = i + 768 < S;
            int2 e0 = eb[i];
            int2 e1 = o1 ? eb[i + 256] : e0;
            int2 e2 = o2 ? eb[i + 512] : e0;
            int2 e3 = o3 ? eb[i + 768] : e0;
            int p0 = atomicAdd(&deg[e0.y - lo], 1);
            int p1 = o1 ? atomicAdd(&deg[e1.y - lo], 1) : 0;
            int p2 = o2 ? atomicAdd(&deg[e2.y - lo], 1) : 0;
            int p3 = o3 ? atomicAdd(&deg[e3.y - lo], 1) : 0;
            col[p0] = e0.x;
            if (o1) col[p1] = e1.x;
            if (o2) col[p2] = e2.x;
            if (o3) col[p3] = e3.x;
        }
        return;
    }

    // ================= t768 branch (R6 form, bf16 parts out) =================
    float* Wl = smem;                                        // 192*20 = 3840
    float (*lx)[16][68] = (float(*)[16][68])(smem + 3840);   // 4*16*68 = 4352
    int bx = bid - nbB - NBUCK;
    int slice = bx & 3;
    int nblk = bx >> 2;
    int wid = tid >> 6, lane = tid & 63;
    int nbase = nblk * 64 + wid * 16;
    int nloc = lane >> 2, og = lane & 3;
    int node = nbase + nloc;
    const float4* xg = (const float4*)x;
    const float4* wg = (const float4*)W;

#pragma unroll
    for (int i = tid; i < 768; i += 256) {
        float4 v = wg[slice * 768 + i];
        *(float4*)&Wl[(i >> 2) * 20 + (i & 3) * 4] = v;
    }
    __syncthreads();

    float4 acc = {0.f, 0.f, 0.f, 0.f};
    const float* lxr = lx[wid][nloc];
#pragma unroll 1
    for (int t = 0; t < 3; ++t) {
#pragma unroll
        for (int r = 0; r < 4; ++r) {
            int f = r * 64 + lane;
            int srow = f >> 4, scol = f & 15;
            int nb = nbase + srow;
            if (nb < n) {
                float4 v = xg[(size_t)nb * 192 + slice * 48 + t * 16 + scol];
                *(float4*)&lx[wid][srow][scol * 4] = v;
            }
        }
#pragma unroll 4
        for (int kk = 0; kk < 16; ++kk) {
            float4 xv = *(const float4*)&lxr[kk * 4];
            int kb = (t * 16 + kk) * 4;
            fma4(xv.x, *(const float4*)&Wl[(kb + 0) * 20 + og * 4], acc);
            fma4(xv.y, *(const float4*)&Wl[(kb + 1) * 20 + og * 4], acc);
            fma4(xv.z, *(const float4*)&Wl[(kb + 2) * 20 + og * 4], acc);
            fma4(xv.w, *(const float4*)&Wl[(kb + 3) * 20 + og * 4], acc);
        }
    }
    if (node < n) {
        uint2* dst = parts + (size_t)slice * n * 4;
        dst[(size_t)node * 4 + og] = f42bf(acc);
    }
}

// ---------- reduce 4 bf16 partials, apply dinv, write bf16 rows ----------
__global__ void k_red4(const uint2* __restrict__ parts, const float* __restrict__ dinv,
                       uint2* __restrict__ u, int n) {
    int g = blockIdx.x * 256 + threadIdx.x;
    if (g >= 4 * n) return;
    size_t stride = (size_t)n * 4;
    float4 a = bf2f4(parts[g]);
    float4 b = bf2f4(parts[g + stride]);
    float4 c = bf2f4(parts[g + 2 * stride]);
    float4 d = bf2f4(parts[g + 3 * stride]);
    float s = dinv[g >> 2];
    float4 r;
    r.x = (a.x + b.x + c.x + d.x) * s;
    r.y = (a.y + b.y + c.y + d.y) * s;
    r.z = (a.z + b.z + c.z + d.z) * s;
    r.w = (a.w + b.w + c.w + d.w) * s;
    u[g] = f42bf(r);
}

// ---------- gather core (bf16 rows): 3 hoisted masked slots + rare tail ----------
__device__ __forceinline__ float4 gather48(const uint2* __restrict__ v2,
                                           const int* __restrict__ col,
                                           int beg, int c, int eslot, int comp, int n) {
    float4 a0 = {0, 0, 0, 0}, a1 = a0, a2 = a0;
    if (c > 0) {
        int i0 = eslot, i1 = eslot + 16, i2 = eslot + 32;
        int s0 = col[beg + (i0 < c ? i0 : 0)];
        int s1 = col[beg + (i1 < c ? i1 : 0)];
        int s2 = col[beg + (i2 < c ? i2 : 0)];
        s0 = (i0 < c) ? s0 : n;
        s1 = (i1 < c) ? s1 : n;
        s2 = (i2 < c) ? s2 : n;
        float4 v0 = bf2f4(v2[(size_t)s0 * 4 + comp]);
        float4 v1 = bf2f4(v2[(size_t)s1 * 4 + comp]);
        float4 v2v = bf2f4(v2[(size_t)s2 * 4 + comp]);
        a0.x += v0.x; a0.y += v0.y; a0.z += v0.z; a0.w += v0.w;
        a1.x += v1.x; a1.y += v1.y; a1.z += v1.z; a1.w += v1.w;
        a2.x += v2v.x; a2.y += v2v.y; a2.z += v2v.z; a2.w += v2v.w;
        for (int i = eslot + 48; i < c; i += 16) {  // rare
            int s = col[beg + i];
            float4 v = bf2f4(v2[(size_t)s * 4 + comp]);
            a0.x += v.x; a0.y += v.y; a0.z += v.z; a0.w += v.w;
        }
    }
    a0.x += a1.x + a2.x;
    a0.y += a1.y + a2.y;
    a0.z += a1.z + a2.z;
    a0.w += a1.w + a2.w;
    for (int off = 4; off < 64; off <<= 1) {
        a0.x += __shfl_xor(a0.x, off, 64);
        a0.y += __shfl_xor(a0.y, off, 64);
        a0.z += __shfl_xor(a0.z, off, 64);
        a0.w += __shfl_xor(a0.w, off, 64);
    }
    return a0;
}

// ---------- layer-1 aggregate: v1 = dinv * relu(dinv*(sum u + self) + b) ----------
__global__ void k_agg16A(const uint2* __restrict__ u, const int* __restrict__ col,
                         const int* __restrict__ offs, const int* __restrict__ cnt,
                         const float* __restrict__ dinv, const float* __restrict__ b,
                         uint2* __restrict__ vout, int n) {
    int wave = threadIdx.x >> 6;
    int node = blockIdx.x * 4 + wave;
    if (node >= n) return;
    int lane = threadIdx.x & 63;
    int eslot = lane >> 2, comp = lane & 3;
    int beg = offs[node], c = cnt[node];
    float4 a0 = gather48(u, col, beg, c, eslot, comp, n);
    if (eslot == 0) {
        float4 self = bf2f4(u[(size_t)node * 4 + comp]);
        float dv = dinv[node];
        float4 bb = ((const float4*)b)[comp];
        float4 r;
        r.x = dv * fmaxf(fmaf(dv, a0.x + self.x, bb.x), 0.f);
        r.y = dv * fmaxf(fmaf(dv, a0.y + self.y, bb.y), 0.f);
        r.z = dv * fmaxf(fmaf(dv, a0.z + self.z, bb.z), 0.f);
        r.w = dv * fmaxf(fmaf(dv, a0.w + self.w, bb.w), 0.f);
        vout[(size_t)node * 4 + comp] = f42bf(r);
    }
}

// ---------- fused aggregate+transform (layer 2) ----------
__global__ void k_agg16F(const uint2* __restrict__ vin, const int* __restrict__ col,
                         const int* __restrict__ offs, const int* __restrict__ cnt,
                         const float* __restrict__ dinv, const float* __restrict__ W,
                         const float* __restrict__ b, uint2* __restrict__ vout, int n) {
    __shared__ float Wl[16 * 20];
    int tid = threadIdx.x;
    if (tid < 64) {
        float4 w = ((const float4*)W)[tid];
        *(float4*)&Wl[(tid >> 2) * 20 + (tid & 3) * 4] = w;
    }
    __syncthreads();
    int wave = tid >> 6;
    int node = blockIdx.x * 4 + wave;
    if (node >= n) return;
    int lane = tid & 63;
    int eslot = lane >> 2, comp = lane & 3;
    int beg = offs[node], c = cnt[node];
    float4 self = bf2f4(vin[(size_t)node * 4 + comp]);
    float dv = dinv[node];
    float4 a0 = gather48(vin, col, beg, c, eslot, comp, n);
    float4 s;
    s.x = dv * (a0.x + self.x);
    s.y = dv * (a0.y + self.y);
    s.z = dv * (a0.z + self.z);
    s.w = dv * (a0.w + self.w);
    float4 p0 = {0, 0, 0, 0}, p1 = p0, p2 = p0, p3 = p0;
    const float* wr = &Wl[comp * 4 * 20];
#pragma unroll
    for (int i2 = 0; i2 < 4; ++i2) {
        float si = (&s.x)[i2];
        const float* row = wr + i2 * 20;
        fma4(si, *(const float4*)&row[((comp ^ 0) << 2)], p0);
        fma4(si, *(const float4*)&row[((comp ^ 1) << 2)], p1);
        fma4(si, *(const float4*)&row[((comp ^ 2) << 2)], p2);
        fma4(si, *(const float4*)&row[((comp ^ 3) << 2)], p3);
    }
    float4 o;
    o.x = p0.x + __shfl_xor(p1.x, 1, 64) + __shfl_xor(p2.x, 2, 64) + __shfl_xor(p3.x, 3, 64);
    o.y = p0.y + __shfl_xor(p1.y, 1, 64) + __shfl_xor(p2.y, 2, 64) + __shfl_xor(p3.y, 3, 64);
    o.z = p0.z + __shfl_xor(p1.z, 1, 64) + __shfl_xor(p2.z, 2, 64) + __shfl_xor(p3.z, 3, 64);
    o.w = p0.w + __shfl_xor(p1.w, 1, 64) + __shfl_xor(p2.w, 2, 64) + __shfl_xor(p3.w, 3, 64);
    if (eslot == 0) {
        float4 bb = ((const float4*)b)[comp];
        float4 r;
        r.x = dv * fmaxf(o.x + bb.x, 0.f);
        r.y = dv * fmaxf(o.y + bb.y, 0.f);
        r.z = dv * fmaxf(o.z + bb.z, 0.f);
        r.w = dv * fmaxf(o.w + bb.w, 0.f);
        vout[(size_t)node * 4 + comp] = f42bf(r);
    }
}

// ---------- layer 3: fused aggregate+transform+W4 projection -> u4p (f32) ----------
__global__ void k_agg16F3(const uint2* __restrict__ vin, const int* __restrict__ col,
                          const int* __restrict__ offs, const int* __restrict__ cnt,
                          const float* __restrict__ dinv, const float* __restrict__ W,
                          const float* __restrict__ b, const float* __restrict__ W4,
                          float4* __restrict__ u4p, int n) {
    __shared__ float Wl[16 * 20];
    __shared__ float W4l[48];
    int tid = threadIdx.x;
    if (tid < 64) {
        float4 w = ((const float4*)W)[tid];
        *(float4*)&Wl[(tid >> 2) * 20 + (tid & 3) * 4] = w;
    } else if (tid >= 64 && tid < 112) {
        W4l[tid - 64] = W4[tid - 64];
    }
    __syncthreads();
    int wave = tid >> 6;
    int node = blockIdx.x * 4 + wave;
    if (node >= n) return;
    int lane = tid & 63;
    int eslot = lane >> 2, comp = lane & 3;
    int beg = offs[node], c = cnt[node];
    float4 self = bf2f4(vin[(size_t)node * 4 + comp]);
    float dv = dinv[node];
    float4 a0 = gather48(vin, col, beg, c, eslot, comp, n);
    float4 s;
    s.x = dv * (a0.x + self.x);
    s.y = dv * (a0.y + self.y);
    s.z = dv * (a0.z + self.z);
    s.w = dv * (a0.w + self.w);
    float4 p0 = {0, 0, 0, 0}, p1 = p0, p2 = p0, p3 = p0;
    const float* wr = &Wl[comp * 4 * 20];
#pragma unroll
    for (int i2 = 0; i2 < 4; ++i2) {
        float si = (&s.x)[i2];
        const float* row = wr + i2 * 20;
        fma4(si, *(const float4*)&row[((comp ^ 0) << 2)], p0);
        fma4(si, *(const float4*)&row[((comp ^ 1) << 2)], p1);
        fma4(si, *(const float4*)&row[((comp ^ 2) << 2)], p2);
        fma4(si, *(const float4*)&row[((comp ^ 3) << 2)], p3);
    }
    float4 o;
    o.x = p0.x + __shfl_xor(p1.x, 1, 64) + __shfl_xor(p2.x, 2, 64) + __shfl_xor(p3.x, 3, 64);
    o.y = p0.y + __shfl_xor(p1.y, 1, 64) + __shfl_xor(p2.y, 2, 64) + __shfl_xor(p3.y, 3, 64);
    o.z = p0.z + __shfl_xor(p1.z, 1, 64) + __shfl_xor(p2.z, 2, 64) + __shfl_xor(p3.z, 3, 64);
    o.w = p0.w + __shfl_xor(p1.w, 1, 64) + __shfl_xor(p2.w, 2, 64) + __shfl_xor(p3.w, 3, 64);
    float4 bb = ((const float4*)b)[comp];
    float4 r;
    r.x = dv * fmaxf(o.x + bb.x, 0.f);
    r.y = dv * fmaxf(o.y + bb.y, 0.f);
    r.z = dv * fmaxf(o.z + bb.z, 0.f);
    r.w = dv * fmaxf(o.w + bb.w, 0.f);
    float q0 = 0.f, q1 = 0.f, q2 = 0.f;
#pragma unroll
    for (int j = 0; j < 4; ++j) {
        float rv = (&r.x)[j];
        const float* w4r = &W4l[(comp * 4 + j) * 3];
        q0 = fmaf(rv, w4r[0], q0);
        q1 = fmaf(rv, w4r[1], q1);
        q2 = fmaf(rv, w4r[2], q2);
    }
    q0 += __shfl_xor(q0, 1, 64); q0 += __shfl_xor(q0, 2, 64);
    q1 += __shfl_xor(q1, 1, 64); q1 += __shfl_xor(q1, 2, 64);
    q2 += __shfl_xor(q2, 1, 64); q2 += __shfl_xor(q2, 2, 64);
    if (lane == 0) u4p[node] = make_float4(q0, q1, q2, 0.f);
}

// ---------- final aggregate + log_softmax (2 nodes/wave, 32 lanes each) ----------
__global__ void k_agg_out(const float4* __restrict__ u4p, const int* __restrict__ col,
                          const int* __restrict__ offs, const int* __restrict__ cnt,
                          const float* __restrict__ dinv, const float* __restrict__ b4,
                          float* __restrict__ out, int n) {
    int half = threadIdx.x >> 5;
    int node = blockIdx.x * 8 + half;
    if (node >= n) return;
    int lane = threadIdx.x & 31;
    int beg = offs[node], c = cnt[node];
    float a0 = 0.f, a1 = 0.f, a2 = 0.f;
    if (c > 0) {
        int i0 = lane, i1 = lane + 32;
        int s0 = col[beg + (i0 < c ? i0 : 0)];
        int s1 = col[beg + (i1 < c ? i1 : 0)];
        s0 = (i0 < c) ? s0 : n;
        s1 = (i1 < c) ? s1 : n;
        float4 v = u4p[s0];
        float4 w = u4p[s1];
        a0 += v.x + w.x; a1 += v.y + w.y; a2 += v.z + w.z;
        for (int i = lane + 64; i < c; i += 32) {  // rare
            float4 y = u4p[col[beg + i]];
            a0 += y.x; a1 += y.y; a2 += y.z;
        }
    }
    for (int off = 1; off < 32; off <<= 1) {
        a0 += __shfl_xor(a0, off, 64);
        a1 += __shfl_xor(a1, off, 64);
        a2 += __shfl_xor(a2, off, 64);
    }
    if (lane == 0) {
        float4 self = u4p[node];
        float dv = dinv[node];
        float v0 = fmaf(dv, a0 + self.x, b4[0]);
        float v1 = fmaf(dv, a1 + self.y, b4[1]);
        float v2 = fmaf(dv, a2 + self.z, b4[2]);
        float m = fmaxf(v0, fmaxf(v1, v2));
        float lse = m + logf(expf(v0 - m) + expf(v1 - m) + expf(v2 - m));
        out[(size_t)node * 3 + 0] = v0 - lse;
        out[(size_t)node * 3 + 1] = v1 - lse;
        out[(size_t)node * 3 + 2] = v2 - lse;
    }
}

extern "C" void kernel_launch(void* const* d_in, const int* in_sizes, int n_in,
                              void* d_out, int out_size, void* d_ws, size_t ws_size,
                              hipStream_t stream) {
    const float* x  = (const float*)d_in[0];
    const void*  ei = d_in[1];
    const float* W1 = (const float*)d_in[2];
    const float* b1 = (const float*)d_in[3];
    const float* W2 = (const float*)d_in[4];
    const float* b2 = (const float*)d_in[5];
    const float* W3 = (const float*)d_in[6];
    const float* b3 = (const float*)d_in[7];
    const float* W4 = (const float*)d_in[8];
    const float* b4 = (const float*)d_in[9];
    float* out = (float*)d_out;

    const int N = in_sizes[0] / 768;
    const int E = in_sizes[1] / 2;

    char* p = (char*)d_ws;
    auto alloc = [&](size_t bytes) {
        void* r = (void*)p;
        p += (bytes + 255) & ~(size_t)255;
        return r;
    };
    int*   cnt   = (int*)alloc((size_t)N * 4);
    int*   offs  = (int*)alloc((size_t)N * 4);
    int*   flag  = (int*)alloc(256);
    int*   gcur  = (int*)alloc(1024);
    int*   done  = (int*)alloc(256);
    float* dinv  = (float*)alloc((size_t)N * 4);
    int*   col   = (int*)alloc((size_t)E * 4);
    uint2* bufU  = (uint2*)alloc((size_t)(N + 1) * 32);   // bf16 rows (16 x 2B)
    uint2* bufA  = (uint2*)alloc((size_t)(N + 1) * 32);
    float4* u4p  = (float4*)alloc((size_t)(N + 1) * 16);
    int2*  ebuf  = (int2*)alloc((size_t)NBUCK * BCAP * 8);   // 37.7 MB
    uint2* parts = (uint2*)alloc((size_t)4 * N * 32);        // 12.8 MB bf16

    const int nbB = DIVUP(E, 2048);
    const int nbT = DIVUP(4 * N, 256);
    const int nbA = DIVUP(N, 4);
    const int nbO = DIVUP(N, 8);
    const int nbX = DIVUP(N, 64) * 4;

    k_init<<<1, 256, 0, stream>>>(ei, flag, gcur, done, bufU, bufA, u4p, N);
    // fused front: bucket(0..nbB) -> signal; build(next 128) spin; t768 rest
    k_front<<<nbB + NBUCK + nbX, 256, 0, stream>>>(ei, flag, gcur, done, ebuf, E, nbB,
                                                   offs, cnt, dinv, col,
                                                   x, W1, parts, N);
    k_red4<<<nbT, 256, 0, stream>>>(parts, dinv, bufU, N);
    k_agg16A<<<nbA, 256, 0, stream>>>(bufU, col, offs, cnt, dinv, b1, bufA, N);
    k_agg16F<<<nbA, 256, 0, stream>>>(bufA, col, offs, cnt, dinv, W2, b2, bufU, N);
    k_agg16F3<<<nbA, 256, 0, stream>>>(bufU, col, offs, cnt, dinv, W3, b3, W4, u4p, N);
    k_agg_out<<<nbO, 256, 0, stream>>>(u4p, col, offs, cnt, dinv, b4, out, N);
}

// Round 19
// 339.601 us; speedup vs baseline: 1.4568x; 1.4568x over previous
//
#include <hip/hip_runtime.h>
#include <hip/hip_bf16.h>

// GCN: 4 layers, D^{-1/2}(A+I)D^{-1/2} aggregation, log_softmax output.
// CSR per call (bucketed build); v = dinv*(h@W) pre-scale, CSR gather,
// post-scale dinv[dst], self-loop folded. Layer1/4 transform BEFORE agg.
// R6 bucket build; R8 gather hoist; R10 t768 R6-form; R13 D1/D2 overlap;
// R14 bf16 gather rows. R15/R18: in-kernel spin handoff REGRESSED (495us:
// bucket-first flood + spin serialization) -> REVERTED to R13/R14 two-
// dispatch front. Kept bf16 parts (halves parts round-trip, ~-4us).

#define DIVUP(a, b) (((a) + (b) - 1) / (b))
#define NBUCK 128
#define BSHIFT 10
#define BCAP 36864

__device__ __forceinline__ int load_idx(const void* ei, int is64, size_t pos) {
    if (is64) return (int)((const long long*)ei)[pos];
    return ((const int*)ei)[pos];
}

// bf16x4 (uint2) <-> float4
__device__ __forceinline__ float4 bf2f4(uint2 q) {
    float4 f;
    f.x = __uint_as_float(q.x << 16);
    f.y = __uint_as_float(q.x & 0xFFFF0000u);
    f.z = __uint_as_float(q.y << 16);
    f.w = __uint_as_float(q.y & 0xFFFF0000u);
    return f;
}
__device__ __forceinline__ unsigned bf1(float v) {
    unsigned u = __float_as_uint(v);
    u += 0x7FFFu + ((u >> 16) & 1u);  // RNE
    return u >> 16;
}
__device__ __forceinline__ uint2 f42bf(float4 f) {
    uint2 q;
    q.x = bf1(f.x) | (bf1(f.y) << 16);
    q.y = bf1(f.z) | (bf1(f.w) << 16);
    return q;
}

// ---------- init: detect edge dtype (wave 0) + zero gcur/pad rows ----------
__global__ void k_init(const void* ei, int* flag, int* gcur,
                       uint2* bufU, uint2* bufA, float4* u4p, int n) {
    int t = threadIdx.x;  // 256
    if (t < 64) {
        const int* p = (const int*)ei;
        bool z = (p[2 * t + 1] == 0);
        unsigned long long m = __ballot(z);
        if (t == 0) *flag = (m == ~0ULL) ? 1 : 0;
    } else if (t < 192) {
        gcur[t - 64] = 0;
    } else if (t < 196) {
        bufU[(size_t)n * 4 + (t - 192)] = make_uint2(0u, 0u);
    } else if (t >= 200 && t < 204) {
        bufA[(size_t)n * 4 + (t - 200)] = make_uint2(0u, 0u);
    } else if (t == 208) {
        u4p[n] = make_float4(0.f, 0.f, 0.f, 0.f);
    }
}

__device__ __forceinline__ void fma4(float s, const float4 w, float4& a) {
    a.x = fmaf(s, w.x, a.x);
    a.y = fmaf(s, w.y, a.y);
    a.z = fmaf(s, w.z, a.z);
    a.w = fmaf(s, w.w, a.w);
}

// ---------- t768 block body (R6 form, bf16 parts out), shared by D1/D2 ----------
__device__ __forceinline__ void t768_body(float* smem, int bx,
                                          const float* __restrict__ x,
                                          const float* __restrict__ W,
                                          uint2* __restrict__ parts, int n) {
    float* Wl = smem;                                        // 192*20 = 3840
    float (*lx)[16][68] = (float(*)[16][68])(smem + 3840);   // 4*16*68 = 4352
    int tid = threadIdx.x;
    int slice = bx & 3;
    int nblk = bx >> 2;
    int wid = tid >> 6, lane = tid & 63;
    int nbase = nblk * 64 + wid * 16;
    int nloc = lane >> 2, og = lane & 3;
    int node = nbase + nloc;
    const float4* xg = (const float4*)x;
    const float4* wg = (const float4*)W;

#pragma unroll
    for (int i = tid; i < 768; i += 256) {
        float4 v = wg[slice * 768 + i];
        *(float4*)&Wl[(i >> 2) * 20 + (i & 3) * 4] = v;
    }
    __syncthreads();

    float4 acc = {0.f, 0.f, 0.f, 0.f};
    const float* lxr = lx[wid][nloc];
#pragma unroll 1
    for (int t = 0; t < 3; ++t) {
#pragma unroll
        for (int r = 0; r < 4; ++r) {
            int f = r * 64 + lane;
            int srow = f >> 4, scol = f & 15;
            int nb = nbase + srow;
            if (nb < n) {
                float4 v = xg[(size_t)nb * 192 + slice * 48 + t * 16 + scol];
                *(float4*)&lx[wid][srow][scol * 4] = v;
            }
        }
#pragma unroll 4
        for (int kk = 0; kk < 16; ++kk) {
            float4 xv = *(const float4*)&lxr[kk * 4];
            int kb = (t * 16 + kk) * 4;
            fma4(xv.x, *(const float4*)&Wl[(kb + 0) * 20 + og * 4], acc);
            fma4(xv.y, *(const float4*)&Wl[(kb + 1) * 20 + og * 4], acc);
            fma4(xv.z, *(const float4*)&Wl[(kb + 2) * 20 + og * 4], acc);
            fma4(xv.w, *(const float4*)&Wl[(kb + 3) * 20 + og * 4], acc);
        }
    }
    if (node < n) {
        uint2* dst = parts + (size_t)slice * n * 4;
        dst[(size_t)node * 4 + og] = f42bf(acc);
    }
}

// ---------- D1: interleaved bucket + t768-A (1 bucket : 2 t768 per group) ----------
__global__ void k_d1(const void* __restrict__ ei, const int* __restrict__ flag,
                     int* __restrict__ gcur, int2* __restrict__ ebuf, int E,
                     const float* __restrict__ x, const float* __restrict__ W,
                     uint2* __restrict__ parts, int n, int nbX) {
    __shared__ float smem[8192];  // 32KB union
    int tid = threadIdx.x;
    int bid = blockIdx.x;
    int g = bid / 3, rr = bid % 3;
    if (rr == 0) {
        int* hist = (int*)smem;
        int* base = hist + NBUCK;
        if (tid < NBUCK) hist[tid] = 0;
        __syncthreads();
        int is64 = *flag;
        int ebase = g * 2048 + tid;
        int s[8], d[8], r[8], bk[8];
        bool ok[8];
#pragma unroll
        for (int j = 0; j < 8; ++j) {
            int e = ebase + j * 256;
            ok[j] = (e < E);
            s[j] = ok[j] ? load_idx(ei, is64, (size_t)e) : 0;
            d[j] = ok[j] ? load_idx(ei, is64, (size_t)E + e) : 0;
            bk[j] = d[j] >> BSHIFT;
        }
#pragma unroll
        for (int j = 0; j < 8; ++j)
            r[j] = ok[j] ? atomicAdd(&hist[bk[j]], 1) : 0;
        __syncthreads();
        if (tid < NBUCK && hist[tid] > 0)
            base[tid] = atomicAdd(&gcur[tid], hist[tid]);
        __syncthreads();
#pragma unroll
        for (int j = 0; j < 8; ++j)
            if (ok[j])
                ebuf[(size_t)bk[j] * BCAP + base[bk[j]] + r[j]] = make_int2(s[j], d[j]);
        return;
    }
    int bx = 2 * g + (rr - 1);
    if (bx >= nbX) return;
    t768_body(smem, bx, x, W, parts, n);
}

// ---------- D2: build (blocks 0..127 first) + t768-B (R11/R13 pattern) ----------
__global__ void k_d2(const int2* __restrict__ ebuf, const int* __restrict__ gcur,
                     int* __restrict__ offs, int* __restrict__ cnt,
                     float* __restrict__ dinv, int* __restrict__ col,
                     const float* __restrict__ x, const float* __restrict__ W,
                     uint2* __restrict__ parts, int n, int xoff, int nbX) {
    __shared__ float smem[8192];
    int tid = threadIdx.x;
    if (blockIdx.x < NBUCK) {
        int* deg = (int*)smem;      // [1024]
        int* ps  = deg + 1024;      // [256]
        int* pbb = deg + 1280;      // [1]
        int b = blockIdx.x;
        int lo = b << BSHIFT;
        deg[tid] = 0; deg[tid + 256] = 0; deg[tid + 512] = 0; deg[tid + 768] = 0;
        if (tid < NBUCK) ps[tid] = (tid < b) ? gcur[tid] : 0;
        __syncthreads();
        for (int off = 1; off < NBUCK; off <<= 1) {
            int add = (tid >= off && tid < NBUCK) ? ps[tid - off] : 0;
            __syncthreads();
            if (tid < NBUCK) ps[tid] += add;
            __syncthreads();
        }
        if (tid == NBUCK - 1) *pbb = ps[tid];
        __syncthreads();
        int bb = *pbb;
        int S = gcur[b];
        const int2* eb = ebuf + (size_t)b * BCAP;
        for (int i = tid; i < S; i += 1024) {
            bool o1 = i + 256 < S, o2 = i + 512 < S, o3 = i + 768 < S;
            int2 e0 = eb[i];
            int2 e1 = o1 ? eb[i + 256] : e0;
            int2 e2 = o2 ? eb[i + 512] : e0;
            int2 e3 = o3 ? eb[i + 768] : e0;
            atomicAdd(&deg[e0.y - lo], 1);
            if (o1) atomicAdd(&deg[e1.y - lo], 1);
            if (o2) atomicAdd(&deg[e2.y - lo], 1);
            if (o3) atomicAdd(&deg[e3.y - lo], 1);
        }
        __syncthreads();
        int d0 = deg[4 * tid], d1 = deg[4 * tid + 1];
        int d2 = deg[4 * tid + 2], d3 = deg[4 * tid + 3];
        int quad = d0 + d1 + d2 + d3;
        ps[tid] = quad;
        __syncthreads();
        for (int off = 1; off < 256; off <<= 1) {
            int add = (tid >= off) ? ps[tid - off] : 0;
            __syncthreads();
            ps[tid] += add;
            __syncthreads();
        }
        int o0 = bb + ps[tid] - quad;
        int o1v = o0 + d0, o2v = o1v + d1, o3v = o2v + d2;
        deg[4 * tid] = o0; deg[4 * tid + 1] = o1v;
        deg[4 * tid + 2] = o2v; deg[4 * tid + 3] = o3v;
        int gg = lo + 4 * tid;
        if (gg < n)     { offs[gg] = o0;      cnt[gg] = d0;     dinv[gg] = rsqrtf((float)(d0 + 1)); }
        if (gg + 1 < n) { offs[gg + 1] = o1v; cnt[gg + 1] = d1; dinv[gg + 1] = rsqrtf((float)(d1 + 1)); }
        if (gg + 2 < n) { offs[gg + 2] = o2v; cnt[gg + 2] = d2; dinv[gg + 2] = rsqrtf((float)(d2 + 1)); }
        if (gg + 3 < n) { offs[gg + 3] = o3v; cnt[gg + 3] = d3; dinv[gg + 3] = rsqrtf((float)(d3 + 1)); }
        __syncthreads();
        for (int i = tid; i < S; i += 1024) {
            bool o1 = i + 256 < S, o2 = i + 512 < S, o3 = i + 768 < S;
            int2 e0 = eb[i];
            int2 e1 = o1 ? eb[i + 256] : e0;
            int2 e2 = o2 ? eb[i + 512] : e0;
            int2 e3 = o3 ? eb[i + 768] : e0;
            int p0 = atomicAdd(&deg[e0.y - lo], 1);
            int p1 = o1 ? atomicAdd(&deg[e1.y - lo], 1) : 0;
            int p2 = o2 ? atomicAdd(&deg[e2.y - lo], 1) : 0;
            int p3 = o3 ? atomicAdd(&deg[e3.y - lo], 1) : 0;
            col[p0] = e0.x;
            if (o1) col[p1] = e1.x;
            if (o2) col[p2] = e2.x;
            if (o3) col[p3] = e3.x;
        }
        return;
    }
    int bx = (blockIdx.x - NBUCK) + xoff;
    if (bx >= nbX) return;
    t768_body(smem, bx, x, W, parts, n);
}

// ---------- reduce 4 bf16 partials, apply dinv, write bf16 rows ----------
__global__ void k_red4(const uint2* __restrict__ parts, const float* __restrict__ dinv,
                       uint2* __restrict__ u, int n) {
    int g = blockIdx.x * 256 + threadIdx.x;
    if (g >= 4 * n) return;
    size_t stride = (size_t)n * 4;
    float4 a = bf2f4(parts[g]);
    float4 b = bf2f4(parts[g + stride]);
    float4 c = bf2f4(parts[g + 2 * stride]);
    float4 d = bf2f4(parts[g + 3 * stride]);
    float s = dinv[g >> 2];
    float4 r;
    r.x = (a.x + b.x + c.x + d.x) * s;
    r.y = (a.y + b.y + c.y + d.y) * s;
    r.z = (a.z + b.z + c.z + d.z) * s;
    r.w = (a.w + b.w + c.w + d.w) * s;
    u[g] = f42bf(r);
}

// ---------- gather core (bf16 rows): 3 hoisted masked slots + rare tail ----------
__device__ __forceinline__ float4 gather48(const uint2* __restrict__ v2,
                                           const int* __restrict__ col,
                                           int beg, int c, int eslot, int comp, int n) {
    float4 a0 = {0, 0, 0, 0}, a1 = a0, a2 = a0;
    if (c > 0) {
        int i0 = eslot, i1 = eslot + 16, i2 = eslot + 32;
        int s0 = col[beg + (i0 < c ? i0 : 0)];
        int s1 = col[beg + (i1 < c ? i1 : 0)];
        int s2 = col[beg + (i2 < c ? i2 : 0)];
        s0 = (i0 < c) ? s0 : n;
        s1 = (i1 < c) ? s1 : n;
        s2 = (i2 < c) ? s2 : n;
        float4 v0 = bf2f4(v2[(size_t)s0 * 4 + comp]);
        float4 v1 = bf2f4(v2[(size_t)s1 * 4 + comp]);
        float4 v2v = bf2f4(v2[(size_t)s2 * 4 + comp]);
        a0.x += v0.x; a0.y += v0.y; a0.z += v0.z; a0.w += v0.w;
        a1.x += v1.x; a1.y += v1.y; a1.z += v1.z; a1.w += v1.w;
        a2.x += v2v.x; a2.y += v2v.y; a2.z += v2v.z; a2.w += v2v.w;
        for (int i = eslot + 48; i < c; i += 16) {  // rare
            int s = col[beg + i];
            float4 v = bf2f4(v2[(size_t)s * 4 + comp]);
            a0.x += v.x; a0.y += v.y; a0.z += v.z; a0.w += v.w;
        }
    }
    a0.x += a1.x + a2.x;
    a0.y += a1.y + a2.y;
    a0.z += a1.z + a2.z;
    a0.w += a1.w + a2.w;
    for (int off = 4; off < 64; off <<= 1) {
        a0.x += __shfl_xor(a0.x, off, 64);
        a0.y += __shfl_xor(a0.y, off, 64);
        a0.z += __shfl_xor(a0.z, off, 64);
        a0.w += __shfl_xor(a0.w, off, 64);
    }
    return a0;
}

// ---------- layer-1 aggregate: v1 = dinv * relu(dinv*(sum u + self) + b) ----------
__global__ void k_agg16A(const uint2* __restrict__ u, const int* __restrict__ col,
                         const int* __restrict__ offs, const int* __restrict__ cnt,
                         const float* __restrict__ dinv, const float* __restrict__ b,
                         uint2* __restrict__ vout, int n) {
    int wave = threadIdx.x >> 6;
    int node = blockIdx.x * 4 + wave;
    if (node >= n) return;
    int lane = threadIdx.x & 63;
    int eslot = lane >> 2, comp = lane & 3;
    int beg = offs[node], c = cnt[node];
    float4 a0 = gather48(u, col, beg, c, eslot, comp, n);
    if (eslot == 0) {
        float4 self = bf2f4(u[(size_t)node * 4 + comp]);
        float dv = dinv[node];
        float4 bb = ((const float4*)b)[comp];
        float4 r;
        r.x = dv * fmaxf(fmaf(dv, a0.x + self.x, bb.x), 0.f);
        r.y = dv * fmaxf(fmaf(dv, a0.y + self.y, bb.y), 0.f);
        r.z = dv * fmaxf(fmaf(dv, a0.z + self.z, bb.z), 0.f);
        r.w = dv * fmaxf(fmaf(dv, a0.w + self.w, bb.w), 0.f);
        vout[(size_t)node * 4 + comp] = f42bf(r);
    }
}

// ---------- fused aggregate+transform (layer 2) ----------
__global__ void k_agg16F(const uint2* __restrict__ vin, const int* __restrict__ col,
                         const int* __restrict__ offs, const int* __restrict__ cnt,
                         const float* __restrict__ dinv, const float* __restrict__ W,
                         const float* __restrict__ b, uint2* __restrict__ vout, int n) {
    __shared__ float Wl[16 * 20];
    int tid = threadIdx.x;
    if (tid < 64) {
        float4 w = ((const float4*)W)[tid];
        *(float4*)&Wl[(tid >> 2) * 20 + (tid & 3) * 4] = w;
    }
    __syncthreads();
    int wave = tid >> 6;
    int node = blockIdx.x * 4 + wave;
    if (node >= n) return;
    int lane = tid & 63;
    int eslot = lane >> 2, comp = lane & 3;
    int beg = offs[node], c = cnt[node];
    float4 self = bf2f4(vin[(size_t)node * 4 + comp]);
    float dv = dinv[node];
    float4 a0 = gather48(vin, col, beg, c, eslot, comp, n);
    float4 s;
    s.x = dv * (a0.x + self.x);
    s.y = dv * (a0.y + self.y);
    s.z = dv * (a0.z + self.z);
    s.w = dv * (a0.w + self.w);
    float4 p0 = {0, 0, 0, 0}, p1 = p0, p2 = p0, p3 = p0;
    const float* wr = &Wl[comp * 4 * 20];
#pragma unroll
    for (int i2 = 0; i2 < 4; ++i2) {
        float si = (&s.x)[i2];
        const float* row = wr + i2 * 20;
        fma4(si, *(const float4*)&row[((comp ^ 0) << 2)], p0);
        fma4(si, *(const float4*)&row[((comp ^ 1) << 2)], p1);
        fma4(si, *(const float4*)&row[((comp ^ 2) << 2)], p2);
        fma4(si, *(const float4*)&row[((comp ^ 3) << 2)], p3);
    }
    float4 o;
    o.x = p0.x + __shfl_xor(p1.x, 1, 64) + __shfl_xor(p2.x, 2, 64) + __shfl_xor(p3.x, 3, 64);
    o.y = p0.y + __shfl_xor(p1.y, 1, 64) + __shfl_xor(p2.y, 2, 64) + __shfl_xor(p3.y, 3, 64);
    o.z = p0.z + __shfl_xor(p1.z, 1, 64) + __shfl_xor(p2.z, 2, 64) + __shfl_xor(p3.z, 3, 64);
    o.w = p0.w + __shfl_xor(p1.w, 1, 64) + __shfl_xor(p2.w, 2, 64) + __shfl_xor(p3.w, 3, 64);
    if (eslot == 0) {
        float4 bb = ((const float4*)b)[comp];
        float4 r;
        r.x = dv * fmaxf(o.x + bb.x, 0.f);
        r.y = dv * fmaxf(o.y + bb.y, 0.f);
        r.z = dv * fmaxf(o.z + bb.z, 0.f);
        r.w = dv * fmaxf(o.w + bb.w, 0.f);
        vout[(size_t)node * 4 + comp] = f42bf(r);
    }
}

// ---------- layer 3: fused aggregate+transform+W4 projection -> u4p (f32) ----------
__global__ void k_agg16F3(const uint2* __restrict__ vin, const int* __restrict__ col,
                          const int* __restrict__ offs, const int* __restrict__ cnt,
                          const float* __restrict__ dinv, const float* __restrict__ W,
                          const float* __restrict__ b, const float* __restrict__ W4,
                          float4* __restrict__ u4p, int n) {
    __shared__ float Wl[16 * 20];
    __shared__ float W4l[48];
    int tid = threadIdx.x;
    if (tid < 64) {
        float4 w = ((const float4*)W)[tid];
        *(float4*)&Wl[(tid >> 2) * 20 + (tid & 3) * 4] = w;
    } else if (tid >= 64 && tid < 112) {
        W4l[tid - 64] = W4[tid - 64];
    }
    __syncthreads();
    int wave = tid >> 6;
    int node = blockIdx.x * 4 + wave;
    if (node >= n) return;
    int lane = tid & 63;
    int eslot = lane >> 2, comp = lane & 3;
    int beg = offs[node], c = cnt[node];
    float4 self = bf2f4(vin[(size_t)node * 4 + comp]);
    float dv = dinv[node];
    float4 a0 = gather48(vin, col, beg, c, eslot, comp, n);
    float4 s;
    s.x = dv * (a0.x + self.x);
    s.y = dv * (a0.y + self.y);
    s.z = dv * (a0.z + self.z);
    s.w = dv * (a0.w + self.w);
    float4 p0 = {0, 0, 0, 0}, p1 = p0, p2 = p0, p3 = p0;
    const float* wr = &Wl[comp * 4 * 20];
#pragma unroll
    for (int i2 = 0; i2 < 4; ++i2) {
        float si = (&s.x)[i2];
        const float* row = wr + i2 * 20;
        fma4(si, *(const float4*)&row[((comp ^ 0) << 2)], p0);
        fma4(si, *(const float4*)&row[((comp ^ 1) << 2)], p1);
        fma4(si, *(const float4*)&row[((comp ^ 2) << 2)], p2);
        fma4(si, *(const float4*)&row[((comp ^ 3) << 2)], p3);
    }
    float4 o;
    o.x = p0.x + __shfl_xor(p1.x, 1, 64) + __shfl_xor(p2.x, 2, 64) + __shfl_xor(p3.x, 3, 64);
    o.y = p0.y + __shfl_xor(p1.y, 1, 64) + __shfl_xor(p2.y, 2, 64) + __shfl_xor(p3.y, 3, 64);
    o.z = p0.z + __shfl_xor(p1.z, 1, 64) + __shfl_xor(p2.z, 2, 64) + __shfl_xor(p3.z, 3, 64);
    o.w = p0.w + __shfl_xor(p1.w, 1, 64) + __shfl_xor(p2.w, 2, 64) + __shfl_xor(p3.w, 3, 64);
    float4 bb = ((const float4*)b)[comp];
    float4 r;
    r.x = dv * fmaxf(o.x + bb.x, 0.f);
    r.y = dv * fmaxf(o.y + bb.y, 0.f);
    r.z = dv * fmaxf(o.z + bb.z, 0.f);
    r.w = dv * fmaxf(o.w + bb.w, 0.f);
    float q0 = 0.f, q1 = 0.f, q2 = 0.f;
#pragma unroll
    for (int j = 0; j < 4; ++j) {
        float rv = (&r.x)[j];
        const float* w4r = &W4l[(comp * 4 + j) * 3];
        q0 = fmaf(rv, w4r[0], q0);
        q1 = fmaf(rv, w4r[1], q1);
        q2 = fmaf(rv, w4r[2], q2);
    }
    q0 += __shfl_xor(q0, 1, 64); q0 += __shfl_xor(q0, 2, 64);
    q1 += __shfl_xor(q1, 1, 64); q1 += __shfl_xor(q1, 2, 64);
    q2 += __shfl_xor(q2, 1, 64); q2 += __shfl_xor(q2, 2, 64);
    if (lane == 0) u4p[node] = make_float4(q0, q1, q2, 0.f);
}

// ---------- final aggregate + log_softmax (2 nodes/wave, 32 lanes each) ----------
__global__ void k_agg_out(const float4* __restrict__ u4p, const int* __restrict__ col,
                          const int* __restrict__ offs, const int* __restrict__ cnt,
                          const float* __restrict__ dinv, const float* __restrict__ b4,
                          float* __restrict__ out, int n) {
    int half = threadIdx.x >> 5;
    int node = blockIdx.x * 8 + half;
    if (node >= n) return;
    int lane = threadIdx.x & 31;
    int beg = offs[node], c = cnt[node];
    float a0 = 0.f, a1 = 0.f, a2 = 0.f;
    if (c > 0) {
        int i0 = lane, i1 = lane + 32;
        int s0 = col[beg + (i0 < c ? i0 : 0)];
        int s1 = col[beg + (i1 < c ? i1 : 0)];
        s0 = (i0 < c) ? s0 : n;
        s1 = (i1 < c) ? s1 : n;
        float4 v = u4p[s0];
        float4 w = u4p[s1];
        a0 += v.x + w.x; a1 += v.y + w.y; a2 += v.z + w.z;
        for (int i = lane + 64; i < c; i += 32) {  // rare
            float4 y = u4p[col[beg + i]];
            a0 += y.x; a1 += y.y; a2 += y.z;
        }
    }
    for (int off = 1; off < 32; off <<= 1) {
        a0 += __shfl_xor(a0, off, 64);
        a1 += __shfl_xor(a1, off, 64);
        a2 += __shfl_xor(a2, off, 64);
    }
    if (lane == 0) {
        float4 self = u4p[node];
        float dv = dinv[node];
        float v0 = fmaf(dv, a0 + self.x, b4[0]);
        float v1 = fmaf(dv, a1 + self.y, b4[1]);
        float v2 = fmaf(dv, a2 + self.z, b4[2]);
        float m = fmaxf(v0, fmaxf(v1, v2));
        float lse = m + logf(expf(v0 - m) + expf(v1 - m) + expf(v2 - m));
        out[(size_t)node * 3 + 0] = v0 - lse;
        out[(size_t)node * 3 + 1] = v1 - lse;
        out[(size_t)node * 3 + 2] = v2 - lse;
    }
}

extern "C" void kernel_launch(void* const* d_in, const int* in_sizes, int n_in,
                              void* d_out, int out_size, void* d_ws, size_t ws_size,
                              hipStream_t stream) {
    const float* x  = (const float*)d_in[0];
    const void*  ei = d_in[1];
    const float* W1 = (const float*)d_in[2];
    const float* b1 = (const float*)d_in[3];
    const float* W2 = (const float*)d_in[4];
    const float* b2 = (const float*)d_in[5];
    const float* W3 = (const float*)d_in[6];
    const float* b3 = (const float*)d_in[7];
    const float* W4 = (const float*)d_in[8];
    const float* b4 = (const float*)d_in[9];
    float* out = (float*)d_out;

    const int N = in_sizes[0] / 768;
    const int E = in_sizes[1] / 2;

    char* p = (char*)d_ws;
    auto alloc = [&](size_t bytes) {
        void* r = (void*)p;
        p += (bytes + 255) & ~(size_t)255;
        return r;
    };
    int*   cnt   = (int*)alloc((size_t)N * 4);
    int*   offs  = (int*)alloc((size_t)N * 4);
    int*   flag  = (int*)alloc(256);
    int*   gcur  = (int*)alloc(1024);
    float* dinv  = (float*)alloc((size_t)N * 4);
    int*   col   = (int*)alloc((size_t)E * 4);
    uint2* bufU  = (uint2*)alloc((size_t)(N + 1) * 32);   // bf16 rows (16 x 2B)
    uint2* bufA  = (uint2*)alloc((size_t)(N + 1) * 32);
    float4* u4p  = (float4*)alloc((size_t)(N + 1) * 16);
    int2*  ebuf  = (int2*)alloc((size_t)NBUCK * BCAP * 8);   // 37.7 MB
    uint2* parts = (uint2*)alloc((size_t)4 * N * 32);        // 12.8 MB bf16

    const int nbB = DIVUP(E, 2048);
    const int nbT = DIVUP(4 * N, 256);
    const int nbA = DIVUP(N, 4);
    const int nbO = DIVUP(N, 8);
    const int nbX = DIVUP(N, 64) * 4;
    const int nbXA = (2 * nbB < nbX) ? 2 * nbB : nbX;  // t768 blocks in D1
    const int nbXB = nbX - nbXA;                       // t768 blocks in D2

    k_init<<<1, 256, 0, stream>>>(ei, flag, gcur, bufU, bufA, u4p, N);
    // D1: bucket || t768-A, interleaved 1:2 for co-residency
    k_d1<<<3 * nbB, 256, 0, stream>>>(ei, flag, gcur, ebuf, E, x, W1, parts, N, nbX);
    // D2: build (128 blocks first) || t768-B
    k_d2<<<NBUCK + nbXB, 256, 0, stream>>>(ebuf, gcur, offs, cnt, dinv, col,
                                           x, W1, parts, N, nbXA, nbX);
    k_red4<<<nbT, 256, 0, stream>>>(parts, dinv, bufU, N);
    k_agg16A<<<nbA, 256, 0, stream>>>(bufU, col, offs, cnt, dinv, b1, bufA, N);
    k_agg16F<<<nbA, 256, 0, stream>>>(bufA, col, offs, cnt, dinv, W2, b2, bufU, N);
    k_agg16F3<<<nbA, 256, 0, stream>>>(bufU, col, offs, cnt, dinv, W3, b3, W4, u4p, N);
    k_agg_out<<<nbO, 256, 0, stream>>>(u4p, col, offs, cnt, dinv, b4, out, N);
}